// Round 4
// baseline (617.260 us; speedup 1.0000x reference)
//
#include <hip/hip_runtime.h>
#include <hip/hip_cooperative_groups.h>
#include <cstddef>

namespace cg = cooperative_groups;

// Problem constants
#define NN 512
#define DD 128
#define HH 4
#define LL 4
#define GHD 32
#define OUTD 128

// ws layout (float offsets) — shared by coop and fallback paths.
// (fallback uses OFF_EP as 4-partial buffer; coop uses its first N*D as EM)
static constexpr size_t OFF_EP  = 0;                               // [4][N][D] / coop: EM [N][D]
static constexpr size_t OFF_ANF = OFF_EP  + (size_t)4 * NN * DD;   // [H][N][D]
static constexpr size_t OFF_DEN = OFF_ANF + (size_t)HH * NN * DD;  // [H][N]
static constexpr size_t OFF_EO  = OFF_DEN + (size_t)HH * NN;       // [H][L][N][GHD]
static constexpr size_t OFF_G   = OFF_EO  + (size_t)HH * LL * NN * GHD; // [H][L][N][GHD]
static constexpr size_t OFF_AG  = OFF_G   + (size_t)HH * LL * NN * GHD; // [H][3][N][GHD]

__device__ __forceinline__ void f4acc(float4& a, const float4& v) {
    a.x += v.x; a.y += v.y; a.z += v.z; a.w += v.w;
}

// ===========================================================================
// Fused cooperative kernel: 512 blocks x 256 threads, 2 blocks/CU demanded.
// Phases: A edge_mean | B Anf+deg (b<128) | sync | C eo panels + g0 | sync |
//         D/E/F layers 1..3 | sync | G final.
// ===========================================================================
__global__ __launch_bounds__(256, 2) void fused_kernel(
    const float* __restrict__ node_feat,
    const float* __restrict__ edge_feat,
    const float* __restrict__ adj,
    const float* __restrict__ W_edge,
    const float* __restrict__ Wn0,
    const float* __restrict__ Wn1,
    const float* __restrict__ Wn2,
    const float* __restrict__ Wn3,
    const float* __restrict__ W_lin,
    const float* __restrict__ b_lin,
    float* __restrict__ ws,
    float* __restrict__ out)
{
    cg::grid_group grid = cg::this_grid();
    const int t = threadIdx.x;
    const int b = blockIdx.x;

    __shared__ __align__(16) float smem[8192];   // 32 KB

    float* EM  = ws + OFF_EP;
    float* ANF = ws + OFF_ANF;
    float* DEN = ws + OFF_DEN;
    float* EO  = ws + OFF_EO;
    float* G   = ws + OFF_G;
    float* AG  = ws + OFF_AG;

    // ---------------- Phase A: edge_mean row b (flat 1KB-per-wave stream) ----
    {
        const float4* efb = reinterpret_cast<const float4*>(edge_feat)
                          + (size_t)b * (NN * DD / 4);
        float4 a0{0,0,0,0}, a1{0,0,0,0}, a2{0,0,0,0}, a3{0,0,0,0};
        #pragma unroll
        for (int m = 0; m < 16; ++m) {
            float4 v0 = efb[(4*m + 0) * 256 + t];
            float4 v1 = efb[(4*m + 1) * 256 + t];
            float4 v2 = efb[(4*m + 2) * 256 + t];
            float4 v3 = efb[(4*m + 3) * 256 + t];
            f4acc(a0, v0); f4acc(a1, v1); f4acc(a2, v2); f4acc(a3, v3);
        }
        f4acc(a0, a1); f4acc(a2, a3); f4acc(a0, a2);
        float4* red = reinterpret_cast<float4*>(smem);
        red[t] = a0;
        __syncthreads();
        if (t < 128) f4acc(red[t], red[t + 128]);
        __syncthreads();
        if (t < 64)  f4acc(red[t], red[t + 64]);
        __syncthreads();
        if (t < 32) {
            float4 m = red[t];
            f4acc(m, red[t + 32]);
            const float inv = 1.0f / (float)NN;
            m.x *= inv; m.y *= inv; m.z *= inv; m.w *= inv;
            reinterpret_cast<float4*>(EM + (size_t)b * DD)[t] = m;
        }
        __syncthreads();   // protect smem before phase B reuse
    }

    // ---------------- Phase B: Anf + deg (blocks 0..127, 16 rows each) ------
    if (b < 128) {
        const int h  = b >> 5;
        const int r0 = (b & 31) * 16;
        float4* As4 = reinterpret_cast<float4*>(smem);
        const float4* Ad4 = reinterpret_cast<const float4*>(
            adj + ((size_t)h * NN + r0) * NN);
        #pragma unroll
        for (int u = 0; u < 8; ++u) As4[t + u * 256] = Ad4[t + u * 256];
        __syncthreads();
        const float* Arow = smem;

        {   // deg: 16 rows x 16-lane groups
            const int rl = t >> 4, ln = t & 15;
            float s = 0.f;
            #pragma unroll 8
            for (int j = ln; j < NN; j += 16) s += Arow[rl * NN + j];
            #pragma unroll
            for (int m = 8; m >= 1; m >>= 1) s += __shfl_xor(s, m);
            if (ln == 0)
                DEN[(size_t)h * NN + r0 + rl] = s + (s == 0.f ? 1.f : 0.f);
        }

        // Anf: c = t&127, rg = t>>7 in [0,2): rows rg, rg+2, ..., rg+14
        const int c = t & 127, rg = t >> 7;
        float c0=0,c1=0,c2=0,c3=0,c4=0,c5=0,c6=0,c7=0;
        #pragma unroll 4
        for (int j = 0; j < NN; ++j) {
            float nf = node_feat[(size_t)j * DD + c];
            c0 += Arow[(rg +  0) * NN + j] * nf;
            c1 += Arow[(rg +  2) * NN + j] * nf;
            c2 += Arow[(rg +  4) * NN + j] * nf;
            c3 += Arow[(rg +  6) * NN + j] * nf;
            c4 += Arow[(rg +  8) * NN + j] * nf;
            c5 += Arow[(rg + 10) * NN + j] * nf;
            c6 += Arow[(rg + 12) * NN + j] * nf;
            c7 += Arow[(rg + 14) * NN + j] * nf;
        }
        float* ab = ANF + ((size_t)h * NN + r0) * DD + c;
        ab[(rg +  0) * DD] = c0; ab[(rg +  2) * DD] = c1;
        ab[(rg +  4) * DD] = c2; ab[(rg +  6) * DD] = c3;
        ab[(rg +  8) * DD] = c4; ab[(rg + 10) * DD] = c5;
        ab[(rg + 12) * DD] = c6; ab[(rg + 14) * DD] = c7;
    }

    grid.sync();

    // ---------------- Phases C..F: per-(h, 4-row) blocks --------------------
    const int h  = b >> 7;
    const int r0 = (b & 127) * 4;
    const int c  = t & 31;
    const int ks = (t >> 5) & 1;   // k/j half split
    const int rr = t >> 6;         // row 0..3
    const int r  = r0 + rr;

    float* emS   = smem;           // [4][128]
    float* anfS  = smem + 512;     // [4][128]
    float* aglS  = smem + 1024;    // [4][32]
    float* pred  = smem + 1152;    // [256]
    float* ArowS = smem + 1408;    // [4][512]

    // stage em + anf rows
    emS[t]        = EM[((size_t)r0 + (t >> 7)) * DD + (t & 127)];
    emS[t + 256]  = EM[((size_t)r0 + 2 + (t >> 7)) * DD + (t & 127)];
    anfS[t]       = ANF[((size_t)h * NN + r0 + (t >> 7)) * DD + (t & 127)];
    anfS[t + 256] = ANF[((size_t)h * NN + r0 + 2 + (t >> 7)) * DD + (t & 127)];
    __syncthreads();

    // Phase C: eo panels l=0..3 (keep l=0 in reg, store l>=1) + g0
    float eo0 = 0.f;
    #pragma unroll
    for (int l = 0; l < 4; ++l) {
        const float* We = W_edge + ((size_t)(h * LL + l) * DD) * GHD;
        float p = 0.f;
        #pragma unroll 8
        for (int k = ks * 64; k < ks * 64 + 64; ++k)
            p += emS[rr * DD + k] * We[(size_t)k * GHD + c];
        pred[t] = p;
        __syncthreads();
        if (ks == 0) {
            float v = pred[t] + pred[t + 32];
            if (l == 0) eo0 = v;
            else EO[((size_t)(h * LL + l) * NN + r) * GHD + c] = v;
        }
        __syncthreads();
    }
    {   // g0
        const float* W0 = Wn0 + (size_t)h * DD * GHD;
        float p = 0.f;
        #pragma unroll 8
        for (int k = ks * 64; k < ks * 64 + 64; ++k)
            p += anfS[rr * DD + k] * W0[(size_t)k * GHD + c];
        pred[t] = p;
        __syncthreads();
        if (ks == 0) {
            float v = pred[t] + pred[t + 32] + eo0;
            v /= DEN[(size_t)h * NN + r];
            v = v > 0.f ? v : 0.f;
            G[((size_t)(h * LL + 0) * NN + r) * GHD + c] = v;
        }
    }

    // Phases D/E/F: layers 1..3
    #pragma unroll
    for (int l = 1; l < 4; ++l) {
        grid.sync();
        if (l == 1) {   // stage this block's 4 A-rows once, reuse for l=2,3
            float4* As4 = reinterpret_cast<float4*>(ArowS);
            const float4* Ad4 = reinterpret_cast<const float4*>(
                adj + ((size_t)h * NN + r0) * NN);
            As4[t]       = Ad4[t];
            As4[t + 256] = Ad4[t + 256];
            __syncthreads();
        }
        // Ag_{l-1}[r][c], j-half per ks
        {
            const float* gp = G + ((size_t)(h * LL + l - 1) * NN) * GHD;
            const float4* Ar4 = reinterpret_cast<const float4*>(ArowS);
            float s = 0.f;
            #pragma unroll 4
            for (int j4 = ks * 64; j4 < ks * 64 + 64; ++j4) {
                float4 a = Ar4[rr * 128 + j4];
                const float* gj = gp + (size_t)j4 * 4 * GHD + c;
                s += a.x * gj[0] + a.y * gj[GHD]
                   + a.z * gj[2 * GHD] + a.w * gj[3 * GHD];
            }
            pred[t] = s;
            __syncthreads();
            if (ks == 0) {
                float ag = pred[t] + pred[t + 32];
                AG[((size_t)(h * 3 + l - 1) * NN + r) * GHD + c] = ag;
                aglS[rr * GHD + c] = ag;
            }
            __syncthreads();
        }
        // k-dot: Anf part (k-half per ks) + Ag_kk blocks (kk parity -> ks)
        const float* Wnb = (l == 1) ? Wn1 : (l == 2) ? Wn2 : Wn3;
        const float* Wnl = Wnb + (size_t)h * (DD + GHD * l) * GHD;
        float p = 0.f;
        #pragma unroll 8
        for (int k = ks * 64; k < ks * 64 + 64; ++k)
            p += anfS[rr * DD + k] * Wnl[(size_t)k * GHD + c];
        #pragma unroll
        for (int kk = 0; kk < l; ++kk) {
            if ((kk & 1) == ks) {
                const float* agv = (kk == l - 1)
                    ? (aglS + rr * GHD)
                    : (AG + ((size_t)(h * 3 + kk) * NN + r) * GHD);
                const float* w = Wnl + ((size_t)(DD + kk * GHD)) * GHD + c;
                #pragma unroll 8
                for (int m = 0; m < GHD; ++m)
                    p += agv[m] * w[(size_t)m * GHD];
            }
        }
        pred[t] = p;
        __syncthreads();
        if (ks == 0) {
            float v = pred[t] + pred[t + 32]
                    + EO[((size_t)(h * LL + l) * NN + r) * GHD + c];
            v /= DEN[(size_t)h * NN + r];
            v = v > 0.f ? v : 0.f;
            G[((size_t)(h * LL + l) * NN + r) * GHD + c] = v;
        }
    }

    grid.sync();

    // ---------------- Phase G: final linear, node n = b ---------------------
    {
        const int n  = b;
        const int o  = t & 127;
        const int hs = t >> 7;   // heads hs, hs+2
        float p = 0.f;
        for (int hh = hs; hh < HH; hh += 2) {
            #pragma unroll
            for (int l2 = 0; l2 < LL; ++l2) {
                const float* gr  = G + ((size_t)(hh * LL + l2) * NN + n) * GHD;
                const float* nfr = node_feat + (size_t)n * DD + l2 * GHD;
                const float* w   = W_lin + (size_t)(hh * DD + l2 * GHD) * OUTD + o;
                #pragma unroll 8
                for (int cc = 0; cc < GHD; ++cc)
                    p += (gr[cc] + nfr[cc]) * w[(size_t)cc * OUTD];
            }
        }
        smem[t] = p;
        __syncthreads();
        if (hs == 0)
            out[(size_t)n * OUTD + o] = smem[o] + smem[o + 128] + b_lin[o];
    }
}

// ===========================================================================
// Fallback pipeline (round-3, known-passing) — used if coop launch fails.
// ===========================================================================
__global__ __launch_bounds__(256) void prep_kernel(
    const float* __restrict__ node_feat,
    const float* __restrict__ edge_feat,
    const float* __restrict__ adj,
    float* __restrict__ ws)
{
    const int t = threadIdx.x;
    const int b = blockIdx.x;
    __shared__ __align__(16) float smem[4 * NN + 256];

    if (b >= 512) {
        const int bb = b - 512;
        const int r  = bb >> 2;
        const int jq = bb & 3;
        const int q  = t & 31;
        const int g  = t >> 5;
        const float4* ef = reinterpret_cast<const float4*>(edge_feat)
                         + ((size_t)r * NN + (size_t)jq * 128) * (DD / 4);
        float4 acc{0,0,0,0};
        #pragma unroll
        for (int k = 0; k < 16; ++k) {
            float4 v = ef[(size_t)(g + 8 * k) * (DD / 4) + q];
            f4acc(acc, v);
        }
        float4* red = reinterpret_cast<float4*>(smem);
        red[t] = acc;
        __syncthreads();
        for (int s = 128; s >= 32; s >>= 1) {
            if (t < s) f4acc(red[t], red[t + s]);
            __syncthreads();
        }
        if (t < 32)
            reinterpret_cast<float4*>(ws + OFF_EP + ((size_t)jq * NN + r) * DD)[t] = red[t];
    } else {
        const int h  = b >> 7;
        const int r0 = (b & 127) * 4;
        const float* A = adj + (size_t)h * NN * NN;
        float* Arow = smem;
        float* dred = smem + 4 * NN;

        for (int idx = t; idx < 4 * NN; idx += 256)
            Arow[idx] = A[(size_t)r0 * NN + idx];
        __syncthreads();
        {
            const int rr = t >> 6, lane = t & 63;
            float s = 0.f;
            #pragma unroll 8
            for (int j = lane; j < NN; j += 64) s += Arow[rr * NN + j];
            dred[t] = s;
            __syncthreads();
            if (t < 4) {
                float d = 0.f;
                for (int j = 0; j < 64; ++j) d += dred[t * 64 + j];
                ws[OFF_DEN + (size_t)h * NN + r0 + t] = d + (d == 0.f ? 1.f : 0.f);
            }
        }
        const int c  = t & 127;
        const int rb = t >> 7;
        float a0 = 0.f, a1 = 0.f;
        #pragma unroll 4
        for (int j = 0; j < NN; ++j) {
            float nf = node_feat[(size_t)j * DD + c];
            a0 += Arow[(rb + 0) * NN + j] * nf;
            a1 += Arow[(rb + 2) * NN + j] * nf;
        }
        float* anf = ws + OFF_ANF + ((size_t)h * NN + r0) * DD;
        anf[(rb + 0) * DD + c] = a0;
        anf[(rb + 2) * DD + c] = a1;
    }
}

__global__ __launch_bounds__(256) void eout_kernel(
    const float* __restrict__ W_edge,
    float* __restrict__ ws)
{
    const int b  = blockIdx.x;
    const int rg = b & 31;
    const int hl = b >> 5;
    const int r0 = rg * 16;
    const int t  = threadIdx.x;
    __shared__ float em[16 * DD];

    const float* P = ws + OFF_EP;
    for (int idx = t; idx < 16 * DD; idx += 256) {
        int r = r0 + (idx >> 7), k = idx & 127;
        size_t o = (size_t)r * DD + k;
        em[idx] = (P[o] + P[(size_t)NN * DD + o]
                 + P[2 * (size_t)NN * DD + o] + P[3 * (size_t)NN * DD + o])
                * (1.0f / (float)NN);
    }
    __syncthreads();

    const int c  = t & 31;
    const int rr = t >> 5;
    const float* We = W_edge + (size_t)hl * DD * GHD;
    float s0 = 0.f, s1 = 0.f;
    #pragma unroll 4
    for (int k = 0; k < DD; ++k) {
        float w = We[(size_t)k * GHD + c];
        s0 += em[rr * DD + k] * w;
        s1 += em[(rr + 8) * DD + k] * w;
    }
    float* eo = ws + OFF_EO + ((size_t)hl * NN + r0) * GHD;
    eo[(size_t)rr * GHD + c]       = s0;
    eo[(size_t)(rr + 8) * GHD + c] = s1;
}

template <int L>
__global__ __launch_bounds__(256) void layer_kernel(
    const float* __restrict__ adj,
    const float* __restrict__ Wn,
    float* __restrict__ ws)
{
    constexpr int KIN = DD + GHD * L;
    const int b   = blockIdx.x;
    const int h   = b >> 8;
    const int r0  = (b & 255) * 2;
    const int t   = threadIdx.x;
    const int rr  = t >> 7;
    const int sub = (t >> 5) & 3;
    const int c   = t & 31;
    const int r   = r0 + rr;

    const float* anf = ws + OFF_ANF;
    const float* den = ws + OFF_DEN;
    const float* eo  = ws + OFF_EO;
    float* G  = ws + OFF_G;
    float* AG = ws + OFF_AG;

    __shared__ float smem[256 + 64 + 256];
    float* agp = smem;
    float* agl = smem + 256;
    float* pp  = smem + 320;

    if (L > 0) {
        const float4* A4 = reinterpret_cast<const float4*>(
            adj + ((size_t)h * NN + r) * NN);
        const float* gp = G + (((size_t)h * LL + (L - 1)) * NN) * GHD;
        float s = 0.f;
        #pragma unroll 4
        for (int j4 = sub * 32; j4 < sub * 32 + 32; ++j4) {
            float4 a = A4[j4];
            const float* gj = gp + (size_t)j4 * 4 * GHD + c;
            s += a.x * gj[0] + a.y * gj[GHD] + a.z * gj[2 * GHD] + a.w * gj[3 * GHD];
        }
        agp[t] = s;
    }
    __syncthreads();
    if (L > 0 && sub == 0) {
        float ag = agp[rr * 128 + c] + agp[rr * 128 + 32 + c]
                 + agp[rr * 128 + 64 + c] + agp[rr * 128 + 96 + c];
        AG[(((size_t)h * 3 + (L - 1)) * NN + r) * GHD + c] = ag;
        agl[rr * GHD + c] = ag;
    }
    __syncthreads();

    float p = 0.f;
    {
        const float* Wnl = Wn + (size_t)h * KIN * GHD;
        const float* ar  = anf + ((size_t)h * NN + r) * DD;
        #pragma unroll 8
        for (int k = sub * 32; k < sub * 32 + 32; ++k)
            p += ar[k] * Wnl[(size_t)k * GHD + c];
        if (sub < L) {
            const float* agk = (sub == L - 1)
                ? (agl + rr * GHD)
                : (AG + (((size_t)h * 3 + sub) * NN + r) * GHD);
            const float* w = Wnl + (size_t)(DD + sub * GHD) * GHD + c;
            #pragma unroll 8
            for (int m = 0; m < GHD; ++m)
                p += agk[m] * w[(size_t)m * GHD];
        }
    }
    pp[t] = p;
    __syncthreads();
    if (sub == 0) {
        float tot = pp[rr * 128 + c] + pp[rr * 128 + 32 + c]
                  + pp[rr * 128 + 64 + c] + pp[rr * 128 + 96 + c]
                  + eo[(((size_t)h * LL + L) * NN + r) * GHD + c];
        float dn = den[(size_t)h * NN + r];
        float gv = tot / dn;
        gv = gv > 0.f ? gv : 0.f;
        G[(((size_t)h * LL + L) * NN + r) * GHD + c] = gv;
    }
}

__global__ __launch_bounds__(256) void final_kernel(
    const float* __restrict__ node_feat,
    const float* __restrict__ W_lin,
    const float* __restrict__ b_lin,
    const float* __restrict__ ws,
    float* __restrict__ out)
{
    const int b  = blockIdx.x;
    const int n  = b >> 1;
    const int oh = b & 1;
    const int t  = threadIdx.x;
    const int ol = t & 63;
    const int ks = t >> 6;
    const int o  = oh * 64 + ol;
    const float* G = ws + OFF_G;
    __shared__ float red[256];

    float p = 0.f;
    #pragma unroll
    for (int l = 0; l < LL; ++l) {
        const float* gr  = G + (((size_t)ks * LL + l) * NN + n) * GHD;
        const float* nfr = node_feat + (size_t)n * DD + l * GHD;
        const float* w   = W_lin + (size_t)(ks * DD + l * GHD) * OUTD + o;
        #pragma unroll 8
        for (int cc = 0; cc < GHD; ++cc)
            p += (gr[cc] + nfr[cc]) * w[(size_t)cc * OUTD];
    }
    red[t] = p;
    __syncthreads();
    if (ks == 0)
        out[(size_t)n * OUTD + o] =
            red[ol] + red[64 + ol] + red[128 + ol] + red[192 + ol] + b_lin[o];
}

// ===========================================================================
extern "C" void kernel_launch(void* const* d_in, const int* in_sizes, int n_in,
                              void* d_out, int out_size, void* d_ws, size_t ws_size,
                              hipStream_t stream)
{
    const float* node_feat = (const float*)d_in[0];
    const float* edge_feat = (const float*)d_in[1];
    const float* adj       = (const float*)d_in[2];
    const float* W_edge    = (const float*)d_in[3];
    const float* Wn0       = (const float*)d_in[4];
    const float* Wn1       = (const float*)d_in[5];
    const float* Wn2       = (const float*)d_in[6];
    const float* Wn3       = (const float*)d_in[7];
    const float* W_lin     = (const float*)d_in[8];
    const float* b_lin     = (const float*)d_in[9];
    float* out = (float*)d_out;
    float* ws  = (float*)d_ws;

    void* args[] = {
        (void*)&node_feat, (void*)&edge_feat, (void*)&adj, (void*)&W_edge,
        (void*)&Wn0, (void*)&Wn1, (void*)&Wn2, (void*)&Wn3,
        (void*)&W_lin, (void*)&b_lin, (void*)&ws, (void*)&out
    };
    hipError_t rc = hipLaunchCooperativeKernel(
        reinterpret_cast<void*>(fused_kernel),
        dim3(512), dim3(256), args, 0, stream);

    if (rc != hipSuccess) {
        // Fallback: known-good round-3 pipeline.
        hipLaunchKernelGGL(prep_kernel, dim3(512 + 2048), dim3(256), 0, stream,
                           node_feat, edge_feat, adj, ws);
        hipLaunchKernelGGL(eout_kernel, dim3(512), dim3(256), 0, stream, W_edge, ws);
        hipLaunchKernelGGL(layer_kernel<0>, dim3(1024), dim3(256), 0, stream, adj, Wn0, ws);
        hipLaunchKernelGGL(layer_kernel<1>, dim3(1024), dim3(256), 0, stream, adj, Wn1, ws);
        hipLaunchKernelGGL(layer_kernel<2>, dim3(1024), dim3(256), 0, stream, adj, Wn2, ws);
        hipLaunchKernelGGL(layer_kernel<3>, dim3(1024), dim3(256), 0, stream, adj, Wn3, ws);
        hipLaunchKernelGGL(final_kernel, dim3(1024), dim3(256), 0, stream,
                           node_feat, W_lin, b_lin, ws, out);
    }
}